// Round 1
// baseline (279.507 us; speedup 1.0000x reference)
//
#include <hip/hip_runtime.h>
#include <hip/hip_bf16.h>
#include <cstdint>

#define DEV __device__ __forceinline__

typedef __attribute__((ext_vector_type(8))) short short8;
typedef __attribute__((ext_vector_type(4))) float f32x4;

DEV unsigned short f2bf(float x) {
    unsigned int u = __float_as_uint(x);
    unsigned int r = (u + 0x7FFFu + ((u >> 16) & 1u)) >> 16;
    return (unsigned short)r;
}
DEV float bf2f(unsigned short h) { return __uint_as_float(((unsigned int)h) << 16); }

// problem sizes
#define LL 4096
#define DM 256
#define DH 128
#define NS 16
#define SB_TOT 8       // 2 streams * 4 batch
#define MROWS 32768    // SB_TOT * LL
#define CHUNK 64
#define NCH 64         // LL / CHUNK

// ---------------- prep: fp32 -> bf16 conversions + A = -exp(A_log) ----------------
__global__ __launch_bounds__(256) void prep_kernel(
    const float* __restrict__ u0, const float* __restrict__ u1,
    const float* __restrict__ inw, const float* __restrict__ outw,
    const float* __restrict__ alog,
    unsigned short* __restrict__ ubf, unsigned short* __restrict__ wbi,
    unsigned short* __restrict__ wbo, float* __restrict__ An)
{
    int i = blockIdx.x * 256 + threadIdx.x;
    if (i < 4194304)       ubf[i] = f2bf(u0[i]);
    else if (i < 8388608)  ubf[i] = f2bf(u1[i - 4194304]);
    else if (i < 8454144){ int j = i - 8388608; wbi[j] = f2bf(inw[j]); }
    else if (i < 8519680){ int j = i - 8454144; wbo[j] = f2bf(outw[j]); }
    else if (i < 8521728){ int j = i - 8519680; An[j] = -__expf(alog[j]); }
}

// ---------------- bf16 MFMA GEMM: C[M,N] = A[M,K] * B[N,K]^T  (K=N=256) ----------------
// 128x128 block tile, BK=32, 4 waves in 2x2, each wave 64x64 (4x4 16x16x32 MFMAs)
template<int F32OUT>
__global__ __launch_bounds__(256) void gemm_bt(
    const unsigned short* __restrict__ A, const unsigned short* __restrict__ B,
    float* __restrict__ Cf, unsigned short* __restrict__ Cb)
{
    __shared__ __align__(16) unsigned short As[128 * 32];
    __shared__ __align__(16) unsigned short Bs[128 * 32];
    const int t = threadIdx.x;
    const int m0 = blockIdx.x * 128, n0 = blockIdx.y * 128;
    const int lane = t & 63, wv = t >> 6;
    const int wm = (wv & 1) * 64, wn = (wv >> 1) * 64;
    const int lr = lane & 15, lk = (lane >> 4) * 8;

    f32x4 acc[4][4] = {};
    for (int kt = 0; kt < 8; ++kt) {
        const int k0 = kt * 32;
        #pragma unroll
        for (int j = 0; j < 2; ++j) {
            int c = t + j * 256;
            int row = c >> 2, col = (c & 3) * 8;
            short8 va = *(const short8*)(A + (size_t)(m0 + row) * 256 + k0 + col);
            short8 vb = *(const short8*)(B + (size_t)(n0 + row) * 256 + k0 + col);
            *(short8*)&As[row * 32 + col] = va;
            *(short8*)&Bs[row * 32 + col] = vb;
        }
        __syncthreads();
        short8 av[4], bv[4];
        #pragma unroll
        for (int i = 0; i < 4; ++i) av[i] = *(const short8*)&As[(wm + i * 16 + lr) * 32 + lk];
        #pragma unroll
        for (int i = 0; i < 4; ++i) bv[i] = *(const short8*)&Bs[(wn + i * 16 + lr) * 32 + lk];
        #pragma unroll
        for (int i = 0; i < 4; ++i)
            #pragma unroll
            for (int j = 0; j < 4; ++j)
                acc[i][j] = __builtin_amdgcn_mfma_f32_16x16x32_bf16(av[i], bv[j], acc[i][j], 0, 0, 0);
        __syncthreads();
    }
    #pragma unroll
    for (int i = 0; i < 4; ++i) {
        #pragma unroll
        for (int j = 0; j < 4; ++j) {
            int r0 = m0 + wm + i * 16 + (lane >> 4) * 4;
            int cc = n0 + wn + j * 16 + lr;
            #pragma unroll
            for (int r = 0; r < 4; ++r) {
                float v = acc[i][j][r];
                if (F32OUT) Cf[(size_t)(r0 + r) * 256 + cc] = v;
                else        Cb[(size_t)(r0 + r) * 256 + cc] = f2bf(v);
            }
        }
    }
}

// ---------------- depthwise conv(K=3, SAME) + SiLU for x and z halves ----------------
__global__ __launch_bounds__(256) void conv_silu(
    const unsigned short* __restrict__ xz, const float* __restrict__ wx,
    const float* __restrict__ wz, float* __restrict__ xf, unsigned short* __restrict__ catb)
{
    int gid = blockIdx.x * 256 + threadIdx.x;   // over SB_TOT*LL*DH
    int c = gid & 127;
    int l = (gid >> 7) & 4095;
    int sb = gid >> 19;
    size_t rowb = ((size_t)sb * LL + l) * DM;
    float xm = (l > 0)    ? bf2f(xz[rowb - DM + c]) : 0.f;
    float x0 = bf2f(xz[rowb + c]);
    float xp = (l < 4095) ? bf2f(xz[rowb + DM + c]) : 0.f;
    float zm = (l > 0)    ? bf2f(xz[rowb - DM + 128 + c]) : 0.f;
    float z0 = bf2f(xz[rowb + 128 + c]);
    float zp = (l < 4095) ? bf2f(xz[rowb + DM + 128 + c]) : 0.f;
    float xv = xm * wx[c * 3] + x0 * wx[c * 3 + 1] + xp * wx[c * 3 + 2];
    float zv = zm * wz[c * 3] + z0 * wz[c * 3 + 1] + zp * wz[c * 3 + 2];
    xv = xv / (1.f + __expf(-xv));
    zv = zv / (1.f + __expf(-zv));
    size_t r = (size_t)sb * LL + l;
    xf[r * DH + c] = xv;
    catb[r * DM + 128 + c] = f2bf(zv);
}

// ---------------- x_proj + dt_proj + softplus fused ----------------
__global__ __launch_bounds__(256) void proj_delta(
    const float* __restrict__ xf, const float* __restrict__ xw,
    const float* __restrict__ dtw, const float* __restrict__ dtb,
    float* __restrict__ delta, float* __restrict__ BC)
{
    __shared__ float xw_s[48 * 129];
    __shared__ float dtw_s[128 * 17];
    __shared__ float dtb_s[128];
    __shared__ float xf_s[16 * 128];
    __shared__ float dbl_s[16 * 48];
    int t = threadIdx.x;
    int sb = blockIdx.x >> 8;
    int l0 = (blockIdx.x & 255) * 16;
    size_t base = (size_t)sb * LL + l0;
    for (int q = t; q < 6144; q += 256) xw_s[(q >> 7) * 129 + (q & 127)] = xw[q];
    for (int q = t; q < 2048; q += 256) dtw_s[(q >> 4) * 17 + (q & 15)] = dtw[q];
    if (t < 128) dtb_s[t] = dtb[t];
    for (int q = t; q < 2048; q += 256) xf_s[q] = xf[base * DH + q];
    __syncthreads();
    for (int q = t; q < 768; q += 256) {
        int l = q / 48, j = q % 48;
        float acc = 0.f;
        const float* xr = &xw_s[j * 129];
        const float* fr = &xf_s[l * 128];
        #pragma unroll 8
        for (int k = 0; k < 128; ++k) acc = fmaf(xr[k], fr[k], acc);
        dbl_s[l * 48 + j] = acc;
    }
    __syncthreads();
    for (int q = t; q < 2048; q += 256) {
        int d = q & 127, l = q >> 7;
        float acc = dtb_s[d];
        #pragma unroll
        for (int r = 0; r < 16; ++r) acc = fmaf(dtw_s[d * 17 + r], dbl_s[l * 48 + r], acc);
        float sp = (acc > 20.f) ? acc : log1pf(__expf(acc));
        delta[(base + l) * DH + d] = sp;
    }
    for (int q = t; q < 512; q += 256) {
        int l = q >> 5, j = q & 31;
        BC[(base + l) * 32 + j] = dbl_s[l * 48 + 16 + j];
    }
}

// ---------------- selective scan, chunked 3-phase ----------------
// phase 1: per-chunk local scan from h=0 -> store (prod dA, h_local_out)
__global__ __launch_bounds__(256) void scan_p1(
    const float* __restrict__ delta, const float* __restrict__ xf,
    const float* __restrict__ BC, const float* __restrict__ An,
    float* __restrict__ P, float* __restrict__ H)
{
    __shared__ float dl_s[CHUNK * 16], u_s[CHUNK * 16], b_s[CHUNK * 16];
    int t = threadIdx.x;
    int ch = blockIdx.x, dg = blockIdx.y, sb = blockIdx.z;
    size_t rb = (size_t)sb * LL + ch * CHUNK;
    for (int q = t; q < CHUNK * 16; q += 256) {
        int row = q >> 4, col = q & 15;
        dl_s[q] = delta[(rb + row) * DH + dg * 16 + col];
        u_s[q]  = xf[(rb + row) * DH + dg * 16 + col];
        b_s[q]  = BC[(rb + row) * 32 + col];
    }
    __syncthreads();
    int nn = t & 15, dl = t >> 4;
    float Adn = An[(dg * 16 + dl) * NS + nn];
    float h = 0.f, p = 1.f;
    #pragma unroll 4
    for (int i = 0; i < CHUNK; ++i) {
        float dt = dl_s[i * 16 + dl];
        float a = __expf(dt * Adn);
        float du = dt * u_s[i * 16 + dl];
        h = fmaf(a, h, du * b_s[i * 16 + nn]);
        p *= a;
    }
    size_t idx = (((size_t)sb * NCH + ch) * 8 + dg) * 256 + t;
    P[idx] = p; H[idx] = h;
}

// phase 2: sequential prefix over chunks; H[idx] becomes h_init of chunk c
__global__ __launch_bounds__(256) void scan_p2(const float* __restrict__ P, float* __restrict__ H)
{
    int t = threadIdx.x, dg = blockIdx.x, sb = blockIdx.y;
    float hin = 0.f;
    for (int c = 0; c < NCH; ++c) {
        size_t idx = (((size_t)sb * NCH + c) * 8 + dg) * 256 + t;
        float p = P[idx], hl = H[idx];
        H[idx] = hin;
        hin = fmaf(p, hin, hl);
    }
}

// phase 3: replay with correct h_init, emit y (+ u*D) into cat buffer (bf16)
__global__ __launch_bounds__(256) void scan_p3(
    const float* __restrict__ delta, const float* __restrict__ xf,
    const float* __restrict__ BC, const float* __restrict__ An,
    const float* __restrict__ Dp, const float* __restrict__ H,
    unsigned short* __restrict__ catb)
{
    __shared__ float dl_s[CHUNK * 16], u_s[CHUNK * 16], b_s[CHUNK * 16], c_s[CHUNK * 16];
    int t = threadIdx.x;
    int ch = blockIdx.x, dg = blockIdx.y, sb = blockIdx.z;
    size_t rb = (size_t)sb * LL + ch * CHUNK;
    for (int q = t; q < CHUNK * 16; q += 256) {
        int row = q >> 4, col = q & 15;
        dl_s[q] = delta[(rb + row) * DH + dg * 16 + col];
        u_s[q]  = xf[(rb + row) * DH + dg * 16 + col];
        b_s[q]  = BC[(rb + row) * 32 + col];
        c_s[q]  = BC[(rb + row) * 32 + 16 + col];
    }
    __syncthreads();
    int nn = t & 15, dl = t >> 4;
    float Adn = An[(dg * 16 + dl) * NS + nn];
    float Dv = Dp[dg * 16 + dl];
    size_t idx = (((size_t)sb * NCH + ch) * 8 + dg) * 256 + t;
    float h = H[idx];
    for (int i = 0; i < CHUNK; ++i) {
        float dt = dl_s[i * 16 + dl];
        float uu = u_s[i * 16 + dl];
        float a = __expf(dt * Adn);
        h = fmaf(a, h, dt * uu * b_s[i * 16 + nn]);
        float yv = h * c_s[i * 16 + nn];
        yv += __shfl_xor(yv, 1);
        yv += __shfl_xor(yv, 2);
        yv += __shfl_xor(yv, 4);
        yv += __shfl_xor(yv, 8);
        if (nn == 0) catb[(rb + i) * DM + dg * 16 + dl] = f2bf(yv + uu * Dv);
    }
}

extern "C" void kernel_launch(void* const* d_in, const int* in_sizes, int n_in,
                              void* d_out, int out_size, void* d_ws, size_t ws_size,
                              hipStream_t stream) {
    const float* u0   = (const float*)d_in[0];
    const float* u1   = (const float*)d_in[1];
    const float* inw  = (const float*)d_in[2];
    const float* cxw  = (const float*)d_in[3];
    const float* czw  = (const float*)d_in[4];
    const float* xpw  = (const float*)d_in[5];
    const float* dtw  = (const float*)d_in[6];
    const float* dtb  = (const float*)d_in[7];
    const float* alog = (const float*)d_in[8];
    const float* Dp   = (const float*)d_in[9];
    const float* outw = (const float*)d_in[10];

    char* ws = (char*)d_ws;
    unsigned short* ubf  = (unsigned short*)(ws + 0);          // 16,777,216 B
    unsigned short* wbi  = (unsigned short*)(ws + 16777216);   // 131,072
    unsigned short* wbo  = (unsigned short*)(ws + 16908288);   // 131,072
    float* An            = (float*)(ws + 17039360);            // 8,192
    float* xf            = (float*)(ws + 17047552);            // 16,777,216
    float* delta         = (float*)(ws + 33824768);            // 16,777,216
    float* BC            = (float*)(ws + 50601984);            // 4,194,304
    unsigned short* catb = (unsigned short*)(ws + 54796288);   // 16,777,216
    float* P             = (float*)(ws + 71573504);            // 4,194,304
    float* H             = (float*)(ws + 75767808);            // 4,194,304  -> end ~80 MB

    unsigned short* xzbf = (unsigned short*)d_out;  // scratch: bf16 xz (16.7 MB of 33.5 MB)
    float* outp = (float*)d_out;

    prep_kernel<<<33288, 256, 0, stream>>>(u0, u1, inw, outw, alog, ubf, wbi, wbo, An);
    gemm_bt<0><<<dim3(256, 2), 256, 0, stream>>>(ubf, wbi, nullptr, xzbf);
    conv_silu<<<16384, 256, 0, stream>>>(xzbf, cxw, czw, xf, catb);
    proj_delta<<<2048, 256, 0, stream>>>(xf, xpw, dtw, dtb, delta, BC);
    scan_p1<<<dim3(64, 8, 8), 256, 0, stream>>>(delta, xf, BC, An, P, H);
    scan_p2<<<dim3(8, 8), 256, 0, stream>>>(P, H);
    scan_p3<<<dim3(64, 8, 8), 256, 0, stream>>>(delta, xf, BC, An, Dp, H, catb);
    gemm_bt<1><<<dim3(256, 2), 256, 0, stream>>>(catb, wbo, outp, nullptr);
}

// Round 3
// 246.203 us; speedup vs baseline: 1.1353x; 1.1353x over previous
//
#include <hip/hip_runtime.h>
#include <hip/hip_bf16.h>
#include <cstdint>

#define DEV __device__ __forceinline__

typedef __attribute__((ext_vector_type(8))) short short8;
typedef __attribute__((ext_vector_type(4))) float f32x4;
typedef __attribute__((ext_vector_type(4))) unsigned short us4;
typedef __attribute__((ext_vector_type(8))) unsigned short us8;

DEV unsigned short f2bf(float x) {
    unsigned int u = __float_as_uint(x);
    unsigned int r = (u + 0x7FFFu + ((u >> 16) & 1u)) >> 16;
    return (unsigned short)r;
}
DEV float bf2f(unsigned short h) { return __uint_as_float(((unsigned int)h) << 16); }

// problem sizes
#define LL 4096
#define DM 256
#define DH 128
#define NS 16
#define SB_TOT 8       // 2 streams * 4 batch
#define CH1 32         // scan chunk length
#define NCH 128        // LL / CH1
#define LOG2E 1.44269504088896f

// ---------------- prep: fp32 -> bf16 conversions + A = -exp(A_log) ----------------
__global__ __launch_bounds__(256) void prep_kernel(
    const float* __restrict__ u0, const float* __restrict__ u1,
    const float* __restrict__ inw, const float* __restrict__ outw,
    const float* __restrict__ alog,
    unsigned short* __restrict__ ubf, unsigned short* __restrict__ wbi,
    unsigned short* __restrict__ wbo, float* __restrict__ An)
{
    int gid = blockIdx.x * 256 + threadIdx.x;
    int i = gid * 4;
    if (i < 4194304) {
        f32x4 v = *(const f32x4*)&u0[i];
        us4 r = { f2bf(v.x), f2bf(v.y), f2bf(v.z), f2bf(v.w) };
        *(us4*)&ubf[i] = r;
    } else if (i < 8388608) {
        int j = i - 4194304;
        f32x4 v = *(const f32x4*)&u1[j];
        us4 r = { f2bf(v.x), f2bf(v.y), f2bf(v.z), f2bf(v.w) };
        *(us4*)&ubf[4194304 + j] = r;
    } else if (i < 8454144) {
        int j = i - 8388608;
        f32x4 v = *(const f32x4*)&inw[j];
        us4 r = { f2bf(v.x), f2bf(v.y), f2bf(v.z), f2bf(v.w) };
        *(us4*)&wbi[j] = r;
    } else if (i < 8519680) {
        int j = i - 8454144;
        f32x4 v = *(const f32x4*)&outw[j];
        us4 r = { f2bf(v.x), f2bf(v.y), f2bf(v.z), f2bf(v.w) };
        *(us4*)&wbo[j] = r;
    } else if (i < 8521728) {
        int j = i - 8519680;
        f32x4 v = *(const f32x4*)&alog[j];
        f32x4 r = { -__expf(v.x), -__expf(v.y), -__expf(v.z), -__expf(v.w) };
        *(f32x4*)&An[j] = r;
    }
}

// ---------------- bf16 MFMA GEMM: C[M,N] = A[M,K] * B[N,K]^T  (K=N=256) ----------------
template<int F32OUT>
__global__ __launch_bounds__(256) void gemm_bt(
    const unsigned short* __restrict__ A, const unsigned short* __restrict__ B,
    float* __restrict__ Cf, unsigned short* __restrict__ Cb)
{
    __shared__ __align__(16) unsigned short As[128 * 32];
    __shared__ __align__(16) unsigned short Bs[128 * 32];
    const int t = threadIdx.x;
    const int m0 = blockIdx.x * 128, n0 = blockIdx.y * 128;
    const int lane = t & 63, wv = t >> 6;
    const int wm = (wv & 1) * 64, wn = (wv >> 1) * 64;
    const int lr = lane & 15, lk = (lane >> 4) * 8;

    f32x4 acc[4][4] = {};
    for (int kt = 0; kt < 8; ++kt) {
        const int k0 = kt * 32;
        #pragma unroll
        for (int j = 0; j < 2; ++j) {
            int c = t + j * 256;
            int row = c >> 2, col = (c & 3) * 8;
            short8 va = *(const short8*)(A + (size_t)(m0 + row) * 256 + k0 + col);
            short8 vb = *(const short8*)(B + (size_t)(n0 + row) * 256 + k0 + col);
            *(short8*)&As[row * 32 + col] = va;
            *(short8*)&Bs[row * 32 + col] = vb;
        }
        __syncthreads();
        short8 av[4], bv[4];
        #pragma unroll
        for (int i = 0; i < 4; ++i) av[i] = *(const short8*)&As[(wm + i * 16 + lr) * 32 + lk];
        #pragma unroll
        for (int i = 0; i < 4; ++i) bv[i] = *(const short8*)&Bs[(wn + i * 16 + lr) * 32 + lk];
        #pragma unroll
        for (int i = 0; i < 4; ++i)
            #pragma unroll
            for (int j = 0; j < 4; ++j)
                acc[i][j] = __builtin_amdgcn_mfma_f32_16x16x32_bf16(av[i], bv[j], acc[i][j], 0, 0, 0);
        __syncthreads();
    }
    #pragma unroll
    for (int i = 0; i < 4; ++i) {
        #pragma unroll
        for (int j = 0; j < 4; ++j) {
            int r0 = m0 + wm + i * 16 + (lane >> 4) * 4;
            int cc = n0 + wn + j * 16 + lr;
            #pragma unroll
            for (int r = 0; r < 4; ++r) {
                float v = acc[i][j][r];
                if (F32OUT) Cf[(size_t)(r0 + r) * 256 + cc] = v;
                else        Cb[(size_t)(r0 + r) * 256 + cc] = f2bf(v);
            }
        }
    }
}

// ---------------- depthwise conv(K=3, SAME) + SiLU, vectorized 8 ch/thread ----------------
__global__ __launch_bounds__(256) void conv_silu(
    const unsigned short* __restrict__ xz, const float* __restrict__ wx,
    const float* __restrict__ wz, float* __restrict__ xf, unsigned short* __restrict__ catb)
{
    int gid = blockIdx.x * 256 + threadIdx.x;   // SB_TOT*LL*16 = 524288
    int g = gid & 15;
    int l = (gid >> 4) & 4095;
    int sb = gid >> 16;
    size_t row = (size_t)sb * LL + l;
    const unsigned short* bp = xz + row * DM;
    int cx = g * 8;
    us8 zz = (us8)0;
    us8 xm = (l > 0)    ? *(const us8*)(bp - DM + cx)        : zz;
    us8 x0 = *(const us8*)(bp + cx);
    us8 xp = (l < 4095) ? *(const us8*)(bp + DM + cx)        : zz;
    us8 zm = (l > 0)    ? *(const us8*)(bp - DM + 128 + cx)  : zz;
    us8 z0 = *(const us8*)(bp + 128 + cx);
    us8 zp = (l < 4095) ? *(const us8*)(bp + DM + 128 + cx)  : zz;

    float xo[8]; us8 zo;
    #pragma unroll
    for (int j = 0; j < 8; ++j) {
        int c = cx + j;
        float xv = bf2f(xm[j]) * wx[c * 3] + bf2f(x0[j]) * wx[c * 3 + 1] + bf2f(xp[j]) * wx[c * 3 + 2];
        float zv = bf2f(zm[j]) * wz[c * 3] + bf2f(z0[j]) * wz[c * 3 + 1] + bf2f(zp[j]) * wz[c * 3 + 2];
        xv = xv / (1.f + __expf(-xv));
        zv = zv / (1.f + __expf(-zv));
        xo[j] = xv;
        zo[j] = f2bf(zv);
    }
    *(f32x4*)&xf[row * DH + cx]     = *(f32x4*)&xo[0];
    *(f32x4*)&xf[row * DH + cx + 4] = *(f32x4*)&xo[4];
    *(us8*)&catb[row * DM + 128 + cx] = zo;
}

// ---------------- x_proj + dt_proj + softplus fused ----------------
__global__ __launch_bounds__(256) void proj_delta(
    const float* __restrict__ xf, const float* __restrict__ xw,
    const float* __restrict__ dtw, const float* __restrict__ dtb,
    float* __restrict__ delta, float* __restrict__ BC)
{
    __shared__ float xw_s[48 * 129];
    __shared__ float dtw_s[128 * 17];
    __shared__ float dtb_s[128];
    __shared__ float xf_s[16 * 128];
    __shared__ float dbl_s[16 * 48];
    int t = threadIdx.x;
    int sb = blockIdx.x >> 8;
    int l0 = (blockIdx.x & 255) * 16;
    size_t base = (size_t)sb * LL + l0;
    for (int q = t; q < 6144; q += 256) xw_s[(q >> 7) * 129 + (q & 127)] = xw[q];
    for (int q = t; q < 2048; q += 256) dtw_s[(q >> 4) * 17 + (q & 15)] = dtw[q];
    if (t < 128) dtb_s[t] = dtb[t];
    for (int q = t; q < 2048; q += 256) xf_s[q] = xf[base * DH + q];
    __syncthreads();
    for (int q = t; q < 768; q += 256) {
        int l = q / 48, j = q % 48;
        float acc = 0.f;
        const float* xr = &xw_s[j * 129];
        const float* fr = &xf_s[l * 128];
        #pragma unroll 8
        for (int k = 0; k < 128; ++k) acc = fmaf(xr[k], fr[k], acc);
        dbl_s[l * 48 + j] = acc;
    }
    __syncthreads();
    for (int q = t; q < 2048; q += 256) {
        int d = q & 127, l = q >> 7;
        float acc = dtb_s[d];
        #pragma unroll
        for (int r = 0; r < 16; ++r) acc = fmaf(dtw_s[d * 17 + r], dbl_s[l * 48 + r], acc);
        float sp = (acc > 20.f) ? acc : log1pf(__expf(acc));
        delta[(base + l) * DH + d] = sp;
    }
    for (int q = t; q < 512; q += 256) {
        int l = q >> 5, j = q & 31;
        BC[(base + l) * 32 + j] = dbl_s[l * 48 + 16 + j];
    }
}

// ---------------- selective scan, chunked 3-phase, n-in-registers ----------------
// phase 1: per-chunk local scan from h=0; store per-(sb,ch,d,n): P=prod(a), H=h_local_end
__global__ __launch_bounds__(128) void scan_p1(
    const float* __restrict__ delta, const float* __restrict__ xf,
    const float* __restrict__ BC, const float* __restrict__ An,
    float* __restrict__ P, float* __restrict__ H)
{
    __shared__ float dt_s[CH1 * 128];
    __shared__ float du_s[CH1 * 128];
    __shared__ float b_s[CH1 * 16];
    int t = threadIdx.x;                 // d channel
    int ch = blockIdx.x, sb = blockIdx.y;
    size_t rb = (size_t)sb * LL + (size_t)ch * CH1;
    for (int q = t; q < CH1 * 32; q += 128) {
        int row = q >> 5, c4 = (q & 31) * 4;
        f32x4 dv = *(const f32x4*)&delta[(rb + row) * DH + c4];
        f32x4 uv = *(const f32x4*)&xf[(rb + row) * DH + c4];
        *(f32x4*)&dt_s[row * 128 + c4] = dv;
        f32x4 duv = dv * uv;
        *(f32x4*)&du_s[row * 128 + c4] = duv;
    }
    {
        int q = t & 127;   // CH1*4 = 128 slots, one pass
        int row = q >> 2, c4 = (q & 3) * 4;
        *(f32x4*)&b_s[row * 16 + c4] = *(const f32x4*)&BC[(rb + row) * 32 + c4];
    }
    __syncthreads();
    float Ar[16];
    #pragma unroll
    for (int n = 0; n < 16; ++n) Ar[n] = An[t * 16 + n] * LOG2E;
    float h[16], p[16];
    #pragma unroll
    for (int n = 0; n < 16; ++n) { h[n] = 0.f; p[n] = 1.f; }
    for (int i = 0; i < CH1; ++i) {
        float dt = dt_s[i * 128 + t];
        float du = du_s[i * 128 + t];
        float bl[16];
        *(f32x4*)&bl[0]  = *(const f32x4*)&b_s[i * 16];
        *(f32x4*)&bl[4]  = *(const f32x4*)&b_s[i * 16 + 4];
        *(f32x4*)&bl[8]  = *(const f32x4*)&b_s[i * 16 + 8];
        *(f32x4*)&bl[12] = *(const f32x4*)&b_s[i * 16 + 12];
        #pragma unroll
        for (int n = 0; n < 16; ++n) {
            float a = exp2f(dt * Ar[n]);
            h[n] = fmaf(a, h[n], du * bl[n]);
            p[n] *= a;
        }
    }
    size_t ob = (((size_t)sb * NCH + ch) * 128 + t) * 16;
    #pragma unroll
    for (int n4 = 0; n4 < 16; n4 += 4) {
        f32x4 pv = { p[n4], p[n4 + 1], p[n4 + 2], p[n4 + 3] };
        f32x4 hv = { h[n4], h[n4 + 1], h[n4 + 2], h[n4 + 3] };
        *(f32x4*)&P[ob + n4] = pv;
        *(f32x4*)&H[ob + n4] = hv;
    }
}

// phase 2: prefix over chunks (block per (sb,d), LDS-staged); H becomes h_init of chunk
__global__ __launch_bounds__(256) void scan_p2(const float* __restrict__ P, float* __restrict__ H)
{
    __shared__ float Ps[NCH * 16], Hs[NCH * 16];
    int t = threadIdx.x;
    int d = blockIdx.x, sb = blockIdx.y;
    for (int q = t; q < NCH * 4; q += 256) {
        int ch = q >> 2, c4 = (q & 3) * 4;
        size_t g = (((size_t)sb * NCH + ch) * 128 + d) * 16 + c4;
        *(f32x4*)&Ps[ch * 16 + c4] = *(const f32x4*)&P[g];
        *(f32x4*)&Hs[ch * 16 + c4] = *(const f32x4*)&H[g];
    }
    __syncthreads();
    if (t < 16) {
        float hin = 0.f;
        for (int c = 0; c < NCH; ++c) {
            float pp = Ps[c * 16 + t], hl = Hs[c * 16 + t];
            Hs[c * 16 + t] = hin;
            hin = fmaf(pp, hin, hl);
        }
    }
    __syncthreads();
    for (int q = t; q < NCH * 4; q += 256) {
        int ch = q >> 2, c4 = (q & 3) * 4;
        size_t g = (((size_t)sb * NCH + ch) * 128 + d) * 16 + c4;
        *(f32x4*)&H[g] = *(const f32x4*)&Hs[ch * 16 + c4];
    }
}

// phase 3: replay with correct h_init; y = sum_n h*C + u*D, within-thread reduce
__global__ __launch_bounds__(128) void scan_p3(
    const float* __restrict__ delta, const float* __restrict__ xf,
    const float* __restrict__ BC, const float* __restrict__ An,
    const float* __restrict__ Dp, const float* __restrict__ H,
    unsigned short* __restrict__ catb)
{
    __shared__ float dt_s[CH1 * 128];
    __shared__ float u_s[CH1 * 128];
    __shared__ float b_s[CH1 * 16];
    __shared__ float c_s[CH1 * 16];
    int t = threadIdx.x;
    int ch = blockIdx.x, sb = blockIdx.y;
    size_t rb = (size_t)sb * LL + (size_t)ch * CH1;
    for (int q = t; q < CH1 * 32; q += 128) {
        int row = q >> 5, c4 = (q & 31) * 4;
        *(f32x4*)&dt_s[row * 128 + c4] = *(const f32x4*)&delta[(rb + row) * DH + c4];
        *(f32x4*)&u_s[row * 128 + c4]  = *(const f32x4*)&xf[(rb + row) * DH + c4];
    }
    {
        int q = t & 127;
        int row = q >> 2, c4 = (q & 3) * 4;
        *(f32x4*)&b_s[row * 16 + c4] = *(const f32x4*)&BC[(rb + row) * 32 + c4];
        *(f32x4*)&c_s[row * 16 + c4] = *(const f32x4*)&BC[(rb + row) * 32 + 16 + c4];
    }
    __syncthreads();
    float Ar[16];
    #pragma unroll
    for (int n = 0; n < 16; ++n) Ar[n] = An[t * 16 + n] * LOG2E;
    float Dv = Dp[t];
    size_t ob = (((size_t)sb * NCH + ch) * 128 + t) * 16;
    float h[16];
    #pragma unroll
    for (int n4 = 0; n4 < 16; n4 += 4) {
        f32x4 hv = *(const f32x4*)&H[ob + n4];
        h[n4] = hv.x; h[n4 + 1] = hv.y; h[n4 + 2] = hv.z; h[n4 + 3] = hv.w;
    }
    for (int i = 0; i < CH1; ++i) {
        float dt = dt_s[i * 128 + t];
        float uu = u_s[i * 128 + t];
        float du = dt * uu;
        float bl[16], cl[16];
        *(f32x4*)&bl[0]  = *(const f32x4*)&b_s[i * 16];
        *(f32x4*)&bl[4]  = *(const f32x4*)&b_s[i * 16 + 4];
        *(f32x4*)&bl[8]  = *(const f32x4*)&b_s[i * 16 + 8];
        *(f32x4*)&bl[12] = *(const f32x4*)&b_s[i * 16 + 12];
        *(f32x4*)&cl[0]  = *(const f32x4*)&c_s[i * 16];
        *(f32x4*)&cl[4]  = *(const f32x4*)&c_s[i * 16 + 4];
        *(f32x4*)&cl[8]  = *(const f32x4*)&c_s[i * 16 + 8];
        *(f32x4*)&cl[12] = *(const f32x4*)&c_s[i * 16 + 12];
        float y0 = uu * Dv, y1 = 0.f, y2 = 0.f, y3 = 0.f;
        #pragma unroll
        for (int n = 0; n < 16; n += 4) {
            float a0 = exp2f(dt * Ar[n]);
            float a1 = exp2f(dt * Ar[n + 1]);
            float a2 = exp2f(dt * Ar[n + 2]);
            float a3 = exp2f(dt * Ar[n + 3]);
            h[n]     = fmaf(a0, h[n],     du * bl[n]);
            h[n + 1] = fmaf(a1, h[n + 1], du * bl[n + 1]);
            h[n + 2] = fmaf(a2, h[n + 2], du * bl[n + 2]);
            h[n + 3] = fmaf(a3, h[n + 3], du * bl[n + 3]);
            y0 = fmaf(h[n],     cl[n],     y0);
            y1 = fmaf(h[n + 1], cl[n + 1], y1);
            y2 = fmaf(h[n + 2], cl[n + 2], y2);
            y3 = fmaf(h[n + 3], cl[n + 3], y3);
        }
        float y = (y0 + y1) + (y2 + y3);
        catb[(rb + i) * DM + t] = f2bf(y);
    }
}

extern "C" void kernel_launch(void* const* d_in, const int* in_sizes, int n_in,
                              void* d_out, int out_size, void* d_ws, size_t ws_size,
                              hipStream_t stream) {
    const float* u0   = (const float*)d_in[0];
    const float* u1   = (const float*)d_in[1];
    const float* inw  = (const float*)d_in[2];
    const float* cxw  = (const float*)d_in[3];
    const float* czw  = (const float*)d_in[4];
    const float* xpw  = (const float*)d_in[5];
    const float* dtw  = (const float*)d_in[6];
    const float* dtb  = (const float*)d_in[7];
    const float* alog = (const float*)d_in[8];
    const float* Dp   = (const float*)d_in[9];
    const float* outw = (const float*)d_in[10];

    // All scratch in ws; d_out written ONLY by the final GEMM (poison-race safe).
    // Aliasing is stream-ordered:
    //   ws[0:16.7M]    ubf (prep->gemm1 only), then P[0:8.4M] + H[8.4M:16.8M] (scan_p1..p3)
    //   ws[16.7M:33.5M] xzbf (gemm1->conv only), then delta (proj_delta..scan_p3)
    char* ws = (char*)d_ws;
    unsigned short* ubf  = (unsigned short*)(ws + 0);          // 16,777,216 B
    float* P             = (float*)(ws + 0);                   //  8,388,608 (after gemm1)
    float* H             = (float*)(ws + 8388608);             //  8,388,608
    unsigned short* xzbf = (unsigned short*)(ws + 16777216);   // 16,777,216
    float* delta         = (float*)(ws + 16777216);            // 16,777,216 (after conv)
    unsigned short* wbi  = (unsigned short*)(ws + 33554432);   //    131,072
    unsigned short* wbo  = (unsigned short*)(ws + 33685504);   //    131,072
    float* An            = (float*)(ws + 33816576);            //      8,192
    float* xf            = (float*)(ws + 33824768);            // 16,777,216
    float* BC            = (float*)(ws + 50601984);            //  4,194,304
    unsigned short* catb = (unsigned short*)(ws + 54796288);   // 16,777,216 -> end 71,573,504

    float* outp = (float*)d_out;

    prep_kernel<<<8322, 256, 0, stream>>>(u0, u1, inw, outw, alog, ubf, wbi, wbo, An);
    gemm_bt<0><<<dim3(256, 2), 256, 0, stream>>>(ubf, wbi, nullptr, xzbf);
    conv_silu<<<2048, 256, 0, stream>>>(xzbf, cxw, czw, xf, catb);
    proj_delta<<<2048, 256, 0, stream>>>(xf, xpw, dtw, dtb, delta, BC);
    scan_p1<<<dim3(NCH, 8), 128, 0, stream>>>(delta, xf, BC, An, P, H);
    scan_p2<<<dim3(128, 8), 256, 0, stream>>>(P, H);
    scan_p3<<<dim3(NCH, 8), 128, 0, stream>>>(delta, xf, BC, An, Dp, H, catb);
    gemm_bt<1><<<dim3(256, 2), 256, 0, stream>>>(catb, wbo, outp, nullptr);
}